// Round 1
// baseline (691.319 us; speedup 1.0000x reference)
//
#include <hip/hip_runtime.h>
#include <math.h>

#define BB 128
#define SS 2048
#define HH 512
#define LL 11

// ---------------------------------------------------------------------------
// Kernel 1: masked row max + argmax.
// x viewed as (B*H) rows of S contiguous floats (reshape semantics).
// One wave (64 lanes) per row; float4 loads, 8 iterations -> 2048 floats.
// First-occurrence argmax semantics (strict > per lane, min-idx tie-break
// across lanes).
// ---------------------------------------------------------------------------
__global__ __launch_bounds__(256) void rowmax_kernel(
    const float* __restrict__ x,
    const int* __restrict__ lengths,
    float* __restrict__ pool,
    int* __restrict__ idx_out) {
  int gid = blockIdx.x * blockDim.x + threadIdx.x;
  int wave = gid >> 6;            // row id r in [0, B*H)
  int lane = threadIdx.x & 63;
  if (wave >= BB * HH) return;
  int b = wave >> 9;              // H == 512
  int len = lengths[b];
  const float4* row = (const float4*)(x + (size_t)wave * SS);

  float best = -INFINITY;
  int bidx = 0;
#pragma unroll
  for (int j = 0; j < 8; ++j) {
    int e = j * 64 + lane;        // float4 index within row
    float4 v = row[e];
    int si = e * 4;
    float a;
    a = (si + 0 < len) ? v.x : -INFINITY;
    if (a > best) { best = a; bidx = si + 0; }
    a = (si + 1 < len) ? v.y : -INFINITY;
    if (a > best) { best = a; bidx = si + 1; }
    a = (si + 2 < len) ? v.z : -INFINITY;
    if (a > best) { best = a; bidx = si + 2; }
    a = (si + 3 < len) ? v.w : -INFINITY;
    if (a > best) { best = a; bidx = si + 3; }
  }
  // cross-lane reduce (64 lanes), first-occurrence tie-break
#pragma unroll
  for (int off = 32; off > 0; off >>= 1) {
    float ov = __shfl_down(best, off);
    int oi = __shfl_down(bidx, off);
    if (ov > best || (ov == best && oi < bidx)) { best = ov; bidx = oi; }
  }
  if (lane == 0) {
    pool[wave] = best;
    idx_out[wave] = bidx;
  }
}

// ---------------------------------------------------------------------------
// Kernel 2: attn = pool @ fc_w.T  -> (B, L). One wave per (b,l).
// attn flat index == wave id (b*L + l).
// ---------------------------------------------------------------------------
__global__ __launch_bounds__(256) void attn_kernel(
    const float* __restrict__ pool,
    const float* __restrict__ fcw,
    float* __restrict__ attn_out) {
  int gid = blockIdx.x * blockDim.x + threadIdx.x;
  int wid = gid >> 6;
  int lane = threadIdx.x & 63;
  if (wid >= BB * LL) return;
  int b = wid / LL;
  int l = wid - b * LL;
  const float* p = pool + b * HH;
  const float* w = fcw + l * HH;
  float sum = 0.f;
#pragma unroll
  for (int k = 0; k < HH / 64; ++k) sum += p[k * 64 + lane] * w[k * 64 + lane];
#pragma unroll
  for (int off = 32; off > 0; off >>= 1) sum += __shfl_down(sum, off);
  if (lane == 0) attn_out[wid] = sum;
}

// ---------------------------------------------------------------------------
// Kernel 3: denom[b,l] = sum_h relu(pool[b,h]*fcw[l,h]) + H*1e-4, b<10
// One wave per (b,l): 110 waves.
// ---------------------------------------------------------------------------
__global__ __launch_bounds__(256) void denom_kernel(
    const float* __restrict__ pool,
    const float* __restrict__ fcw,
    float* __restrict__ denom) {
  int gid = blockIdx.x * blockDim.x + threadIdx.x;
  int wid = gid >> 6;
  int lane = threadIdx.x & 63;
  if (wid >= 10 * LL) return;
  int b = wid / LL;
  int l = wid - b * LL;
  const float* p = pool + b * HH;
  const float* w = fcw + l * HH;
  float sum = 0.f;
#pragma unroll
  for (int k = 0; k < HH / 64; ++k)
    sum += fmaxf(p[k * 64 + lane] * w[k * 64 + lane], 0.f);
#pragma unroll
  for (int off = 32; off > 0; off >>= 1) sum += __shfl_down(sum, off);
  if (lane == 0) denom[wid] = sum + (float)HH * 1e-4f;
}

// ---------------------------------------------------------------------------
// Kernel 4: total[b,hh] = sum_l (relu(pool*w)+1e-4) * 100/denom[b,l];
// scatter-add into ch2[b*S + idx[b,hh]]. 10 blocks x 512 threads.
// ch2 (10*S floats) must be pre-zeroed.
// ---------------------------------------------------------------------------
__global__ __launch_bounds__(512) void scatter_kernel(
    const float* __restrict__ pool,
    const float* __restrict__ fcw,
    const float* __restrict__ denom,
    const int* __restrict__ idx_in,
    float* __restrict__ ch2) {
  int b = blockIdx.x;            // 0..9
  int hh = threadIdx.x;          // 0..511
  __shared__ float sden[LL];
  if (threadIdx.x < LL) sden[threadIdx.x] = 100.f / denom[b * LL + threadIdx.x];
  __syncthreads();
  float p = pool[b * HH + hh];
  float total = 0.f;
#pragma unroll
  for (int l = 0; l < LL; ++l) {
    float c = fmaxf(p * fcw[l * HH + hh], 0.f) + 1e-4f;
    total += c * sden[l];
  }
  atomicAdd(&ch2[b * SS + idx_in[b * HH + hh]], total);
}

// ---------------------------------------------------------------------------
// Kernel 5: finalize contri_out = concat(contri, ch2) -> (B, S, 3), written
// after the attn block in d_out. Each thread handles one (b,s): 12B write,
// consecutive lanes -> contiguous 768B per wave.
// ---------------------------------------------------------------------------
__global__ __launch_bounds__(256) void finalize_kernel(
    const float* __restrict__ contri,
    const float* __restrict__ ch2,
    float* __restrict__ out2) {
  int t = blockIdx.x * blockDim.x + threadIdx.x;   // [0, B*S)
  if (t >= BB * SS) return;
  float c0 = contri[t * 2 + 0];
  float c1 = contri[t * 2 + 1];
  float c2 = (t < 10 * SS) ? ch2[t] : 0.f;
  out2[t * 3 + 0] = c0;
  out2[t * 3 + 1] = c1;
  out2[t * 3 + 2] = c2;
}

extern "C" void kernel_launch(void* const* d_in, const int* in_sizes, int n_in,
                              void* d_out, int out_size, void* d_ws, size_t ws_size,
                              hipStream_t stream) {
  // inputs (setup_inputs order): find_contri, code_output, lengths, contri, fc_w
  const float* code_output = (const float*)d_in[1];
  const int* lengths = (const int*)d_in[2];
  const float* contri = (const float*)d_in[3];
  const float* fcw = (const float*)d_in[4];

  float* out = (float*)d_out;            // attn at [0, B*L)
  float* out2 = out + BB * LL;           // contri_out at [B*L, ...)

  // workspace layout (floats)
  float* ws = (float*)d_ws;
  float* pool = ws;                      // B*H = 65536
  int* idx = (int*)(ws + 65536);         // B*H = 65536
  float* denom = ws + 131072;            // 110
  float* ch2 = ws + 131200;              // 10*S = 20480

  // zero the scatter target (poisoned to 0xAA before every timed launch)
  hipMemsetAsync(ch2, 0, (size_t)10 * SS * sizeof(float), stream);

  // 1. masked row max/argmax: 65536 waves -> 16384 blocks of 256
  rowmax_kernel<<<(BB * HH * 64) / 256, 256, 0, stream>>>(code_output, lengths,
                                                          pool, idx);
  // 2. attn: 1408 waves -> 352 blocks
  attn_kernel<<<(BB * LL * 64 + 255) / 256, 256, 0, stream>>>(pool, fcw, out);
  // 3. denom: 110 waves
  denom_kernel<<<(10 * LL * 64 + 255) / 256, 256, 0, stream>>>(pool, fcw, denom);
  // 4. scatter: 10 blocks x 512
  scatter_kernel<<<10, 512, 0, stream>>>(pool, fcw, denom, idx, ch2);
  // 5. finalize: 262144 threads
  finalize_kernel<<<(BB * SS + 255) / 256, 256, 0, stream>>>(contri, ch2, out2);
}

// Round 3
// 653.953 us; speedup vs baseline: 1.0571x; 1.0571x over previous
//
#include <hip/hip_runtime.h>
#include <math.h>

#define BB 128
#define SS 2048
#define HH 512
#define LL 11

typedef float vf4 __attribute__((ext_vector_type(4)));

// ---------------------------------------------------------------------------
// Kernel 1: masked row max + argmax over (B*H) contiguous rows of S floats.
// One wave per row, float4 nontemporal loads (pure streaming, no reuse).
// ---------------------------------------------------------------------------
__global__ __launch_bounds__(256) void rowmax_kernel(
    const float* __restrict__ x,
    const int* __restrict__ lengths,
    float* __restrict__ pool,
    int* __restrict__ idx_out) {
  int gid = blockIdx.x * blockDim.x + threadIdx.x;
  int wave = gid >> 6;            // row id in [0, B*H)
  int lane = threadIdx.x & 63;
  if (wave >= BB * HH) return;
  int b = wave >> 9;              // H == 512
  int len = lengths[b];
  const vf4* row = (const vf4*)(x + (size_t)wave * SS);

  float best = -INFINITY;
  int bidx = 0;
#pragma unroll
  for (int j = 0; j < 8; ++j) {
    int e = j * 64 + lane;
    vf4 v = __builtin_nontemporal_load(&row[e]);
    int si = e * 4;
    float a;
    a = (si + 0 < len) ? v.x : -INFINITY;
    if (a > best) { best = a; bidx = si + 0; }
    a = (si + 1 < len) ? v.y : -INFINITY;
    if (a > best) { best = a; bidx = si + 1; }
    a = (si + 2 < len) ? v.z : -INFINITY;
    if (a > best) { best = a; bidx = si + 2; }
    a = (si + 3 < len) ? v.w : -INFINITY;
    if (a > best) { best = a; bidx = si + 3; }
  }
  // cross-lane reduce, first-occurrence tie-break (min index on equal value)
#pragma unroll
  for (int off = 32; off > 0; off >>= 1) {
    float ov = __shfl_down(best, off);
    int oi = __shfl_down(bidx, off);
    if (ov > best || (ov == best && oi < bidx)) { best = ov; bidx = oi; }
  }
  if (lane == 0) {
    pool[wave] = best;
    idx_out[wave] = bidx;
  }
}

// ---------------------------------------------------------------------------
// Kernel 2: fused epilogue, one dispatch.
//   blocks [0,10):        per-batch denom + total + LDS scatter + output row
//   blocks [10,138):      attn = pool @ fc_w.T for b = blockIdx-10
//   blocks [138,...):     plain contri copy rows for b >= 10
// ---------------------------------------------------------------------------
__global__ __launch_bounds__(256) void epilogue_kernel(
    const float* __restrict__ pool,
    const int* __restrict__ idx_in,
    const float* __restrict__ fcw,
    const float* __restrict__ contri,
    float* __restrict__ attn_out,
    float* __restrict__ out2) {
  int tid = threadIdx.x;
  int wv = tid >> 6;
  int lane = tid & 63;

  if (blockIdx.x < 10) {
    // ---- special batch: contributions + LDS scatter + row write ----
    int b = blockIdx.x;
    __shared__ float sp[HH];     // pool row
    __shared__ float sden[LL];   // 100/denom
    __shared__ float sch[SS];    // scatter target (ch2 row)

    for (int h = tid; h < HH; h += 256) sp[h] = pool[b * HH + h];
    for (int s = tid; s < SS; s += 256) sch[s] = 0.f;
    __syncthreads();

    // denom[l] = sum_h relu(p*w) + H*1e-4 ; store reciprocal*100
    for (int l = wv; l < LL; l += 4) {
      float s = 0.f;
#pragma unroll
      for (int k = 0; k < HH / 64; ++k) {
        int h = k * 64 + lane;
        s += fmaxf(sp[h] * fcw[l * HH + h], 0.f);
      }
#pragma unroll
      for (int off = 32; off > 0; off >>= 1) s += __shfl_down(s, off);
      if (lane == 0) sden[l] = 100.f / (s + (float)HH * 1e-4f);
    }
    __syncthreads();

    // total[hh] and scatter into LDS
    for (int hh = tid; hh < HH; hh += 256) {
      float p = sp[hh];
      float tot = 0.f;
#pragma unroll
      for (int l = 0; l < LL; ++l)
        tot += (fmaxf(p * fcw[l * HH + hh], 0.f) + 1e-4f) * sden[l];
      atomicAdd(&sch[idx_in[b * HH + hh]], tot);
    }
    __syncthreads();

    // write output rows: (contri0, contri1, ch2)
    for (int s = tid; s < SS; s += 256) {
      int t = b * SS + s;
      out2[t * 3 + 0] = contri[t * 2 + 0];
      out2[t * 3 + 1] = contri[t * 2 + 1];
      out2[t * 3 + 2] = sch[s];
    }
  } else if (blockIdx.x < 10 + BB) {
    // ---- attn for one batch ----
    int b = blockIdx.x - 10;
    const float* p = pool + b * HH;
    for (int l = wv; l < LL; l += 4) {
      const float* w = fcw + l * HH;
      float s = 0.f;
#pragma unroll
      for (int k = 0; k < HH / 64; ++k) s += p[k * 64 + lane] * w[k * 64 + lane];
#pragma unroll
      for (int off = 32; off > 0; off >>= 1) s += __shfl_down(s, off);
      if (lane == 0) attn_out[b * LL + l] = s;
    }
  } else {
    // ---- plain copy rows for b >= 10 ----
    int i = (blockIdx.x - (10 + BB)) * 256 + tid;
    int t = 10 * SS + i;
    if (t < BB * SS) {
      out2[t * 3 + 0] = contri[t * 2 + 0];
      out2[t * 3 + 1] = contri[t * 2 + 1];
      out2[t * 3 + 2] = 0.f;
    }
  }
}

extern "C" void kernel_launch(void* const* d_in, const int* in_sizes, int n_in,
                              void* d_out, int out_size, void* d_ws, size_t ws_size,
                              hipStream_t stream) {
  // inputs: find_contri, code_output, lengths, contri, fc_w
  const float* code_output = (const float*)d_in[1];
  const int* lengths = (const int*)d_in[2];
  const float* contri = (const float*)d_in[3];
  const float* fcw = (const float*)d_in[4];

  float* out = (float*)d_out;            // attn at [0, B*L)
  float* out2 = out + BB * LL;           // contri_out after

  float* ws = (float*)d_ws;
  float* pool = ws;                      // B*H floats
  int* idx = (int*)(ws + BB * HH);       // B*H ints

  rowmax_kernel<<<(BB * HH * 64) / 256, 256, 0, stream>>>(code_output, lengths,
                                                          pool, idx);

  int copy_blocks = ((BB - 10) * SS + 255) / 256;   // 944
  epilogue_kernel<<<10 + BB + copy_blocks, 256, 0, stream>>>(pool, idx, fcw,
                                                             contri, out, out2);
}